// Round 2
// baseline (1697.207 us; speedup 1.0000x reference)
//
#include <hip/hip_runtime.h>
#include <math.h>

#define B_ 8
#define S_ 1024
#define DM 512
#define H_ 8
#define DH 64

// ---------------------------------------------------------------------------
// Generic tiled fp32 GEMM: C = A(MxK) @ B(KxN), all row-major.
// 64x64 block tile, 256 threads, 4x4 microtile per thread, BK=16.
// ---------------------------------------------------------------------------
__global__ __launch_bounds__(256) void gemm_f32(
    const float* __restrict__ A, const float* __restrict__ Bm,
    float* __restrict__ C, int M, int N, int K) {
  __shared__ float As[16][68];  // [k][row], 68 keeps float4 alignment + breaks bank stride
  __shared__ float Bs[16][64];  // [k][col]
  const int t = threadIdx.x;
  const int tx = t & 15, ty = t >> 4;
  const int row0 = blockIdx.y * 64;
  const int col0 = blockIdx.x * 64;
  float acc[4][4] = {{0.f}};
  for (int k0 = 0; k0 < K; k0 += 16) {
#pragma unroll
    for (int i = 0; i < 4; i++) {
      int f = t + i * 256;
      int r = f >> 4, kk = f & 15;
      As[kk][r] = A[(size_t)(row0 + r) * K + k0 + kk];
    }
#pragma unroll
    for (int i = 0; i < 4; i++) {
      int f = t + i * 256;
      int kk = f >> 6, c = f & 63;
      Bs[kk][c] = Bm[(size_t)(k0 + kk) * N + col0 + c];
    }
    __syncthreads();
#pragma unroll
    for (int kk = 0; kk < 16; kk++) {
      float4 a = *reinterpret_cast<const float4*>(&As[kk][ty * 4]);
      float4 b = *reinterpret_cast<const float4*>(&Bs[kk][tx * 4]);
      float av[4] = {a.x, a.y, a.z, a.w};
      float bv[4] = {b.x, b.y, b.z, b.w};
#pragma unroll
      for (int i = 0; i < 4; i++)
#pragma unroll
        for (int j = 0; j < 4; j++) acc[i][j] += av[i] * bv[j];
    }
    __syncthreads();
  }
#pragma unroll
  for (int i = 0; i < 4; i++) {
    float4 o = make_float4(acc[i][0], acc[i][1], acc[i][2], acc[i][3]);
    *reinterpret_cast<float4*>(&C[(size_t)(row0 + ty * 4 + i) * N + col0 + tx * 4]) = o;
  }
}

// ---------------------------------------------------------------------------
// scores_avg: out1[b,i,j] = mask ? -1e9 : edge[b,i,j] + dot(Q[b,i,:],K[b,j,:])/64
// (sum over heads of per-head dots on disjoint 64-slices == full 512-dim dot;
//  /8 for sqrt(Dh), /8 for head average)
// ---------------------------------------------------------------------------
__global__ __launch_bounds__(256) void scores_avg_gemm(
    const float* __restrict__ Qp, const float* __restrict__ Kp,
    const int* __restrict__ mask, const float* __restrict__ edge,
    float* __restrict__ out1) {
  const int b = blockIdx.z;
  const int i0 = blockIdx.y * 64;
  const int j0 = blockIdx.x * 64;
  const float* A = Qp + (size_t)b * S_ * DM;
  const float* Bm = Kp + (size_t)b * S_ * DM;
  __shared__ float As[16][68];
  __shared__ float Bs[16][68];
  const int t = threadIdx.x;
  const int tx = t & 15, ty = t >> 4;
  float acc[4][4] = {{0.f}};
  for (int k0 = 0; k0 < DM; k0 += 16) {
#pragma unroll
    for (int i = 0; i < 4; i++) {
      int f = t + i * 256;
      int r = f >> 4, kk = f & 15;
      As[kk][r] = A[(size_t)(i0 + r) * DM + k0 + kk];
      Bs[kk][r] = Bm[(size_t)(j0 + r) * DM + k0 + kk];
    }
    __syncthreads();
#pragma unroll
    for (int kk = 0; kk < 16; kk++) {
      float4 a = *reinterpret_cast<const float4*>(&As[kk][ty * 4]);
      float4 b4 = *reinterpret_cast<const float4*>(&Bs[kk][tx * 4]);
      float av[4] = {a.x, a.y, a.z, a.w};
      float bv[4] = {b4.x, b4.y, b4.z, b4.w};
#pragma unroll
      for (int i = 0; i < 4; i++)
#pragma unroll
        for (int j = 0; j < 4; j++) acc[i][j] += av[i] * bv[j];
    }
    __syncthreads();
  }
#pragma unroll
  for (int i = 0; i < 4; i++) {
    int gi = i0 + ty * 4 + i;
    size_t rowb = ((size_t)b * S_ + gi) * S_;
#pragma unroll
    for (int j = 0; j < 4; j++) {
      int gj = j0 + tx * 4 + j;
      size_t idx = rowb + gj;
      float v = acc[i][j] * (1.0f / 64.0f) + edge[idx];
      out1[idx] = mask[idx] ? -1e9f : v;
    }
  }
}

// ---------------------------------------------------------------------------
// Flash attention (fp32): one block per (b,h, 64-row Q tile). K-tiles of 32.
// Thread t: query row r = t>>2; score j-group jg = t&3 (8 scores);
// owns output d-columns c0 = jg*16 .. +16. Online softmax per row (the 4
// threads of a row redundantly compute identical m/l from LDS scores).
// scores = qk/8 + edge, masked -> -1e9 (exactly reproduces reference,
// including all-masked rows -> uniform 1/1024 attention).
// ---------------------------------------------------------------------------
__global__ __launch_bounds__(256) void flash_attn(
    const float* __restrict__ Qp, const float* __restrict__ Kp,
    const float* __restrict__ Vp, const int* __restrict__ mask,
    const float* __restrict__ edge, float* __restrict__ ctx) {
  const int bh = blockIdx.y;
  const int b = bh >> 3, h = bh & 7;
  const int q0 = blockIdx.x * 64;
  const int t = threadIdx.x;
  const int r = t >> 2;
  const int jg = t & 3;
  const int c0 = jg * 16;
  __shared__ float Qs[64][68];
  __shared__ float Ks[32][68];
  __shared__ float Vs[32][68];
  __shared__ float Ss[64][33];
  const size_t bS = (size_t)b * S_;
  // stage Q tile (rows q0..q0+63, head-slice h*64..+64)
#pragma unroll
  for (int i = 0; i < 16; i++) {
    int f = t + i * 256;
    int rr = f >> 6, d = f & 63;
    Qs[rr][d] = Qp[(bS + q0 + rr) * DM + h * DH + d];
  }
  __syncthreads();
  float4 q[16];
#pragma unroll
  for (int i = 0; i < 16; i++)
    q[i] = *reinterpret_cast<const float4*>(&Qs[r][i * 4]);

  float m_run = -INFINITY, l_run = 0.f;
  float acc[16];
#pragma unroll
  for (int i = 0; i < 16; i++) acc[i] = 0.f;

  for (int kb = 0; kb < S_; kb += 32) {
    __syncthreads();  // protect Ks/Vs/Ss from previous iteration's readers
#pragma unroll
    for (int i = 0; i < 8; i++) {
      int f = t + i * 256;
      int jj = f >> 6, d = f & 63;
      Ks[jj][d] = Kp[(bS + kb + jj) * DM + h * DH + d];
      Vs[jj][d] = Vp[(bS + kb + jj) * DM + h * DH + d];
    }
    __syncthreads();
    // scores for (row r, j = jg*8 .. jg*8+8)
#pragma unroll
    for (int jj = 0; jj < 8; jj++) {
      int j = jg * 8 + jj;
      float s = 0.f;
#pragma unroll
      for (int i = 0; i < 16; i++) {
        float4 kv = *reinterpret_cast<const float4*>(&Ks[j][i * 4]);
        s += q[i].x * kv.x + q[i].y * kv.y + q[i].z * kv.z + q[i].w * kv.w;
      }
      size_t eidx = (bS + q0 + r) * (size_t)S_ + kb + j;
      s = s * 0.125f + edge[eidx];
      if (mask[eidx]) s = -1e9f;
      Ss[r][j] = s;
    }
    __syncthreads();
    // online softmax update + PV accumulate
    float m_tile = -INFINITY;
#pragma unroll
    for (int j = 0; j < 32; j++) m_tile = fmaxf(m_tile, Ss[r][j]);
    float m_new = fmaxf(m_run, m_tile);
    float alpha = __expf(m_run - m_new);  // exp(-inf)=0 on first tile
    l_run *= alpha;
#pragma unroll
    for (int i = 0; i < 16; i++) acc[i] *= alpha;
    for (int j = 0; j < 32; j++) {
      float p = __expf(Ss[r][j] - m_new);
      l_run += p;
#pragma unroll
      for (int i = 0; i < 4; i++) {
        float4 vv = *reinterpret_cast<const float4*>(&Vs[j][c0 + i * 4]);
        acc[i * 4 + 0] += p * vv.x;
        acc[i * 4 + 1] += p * vv.y;
        acc[i * 4 + 2] += p * vv.z;
        acc[i * 4 + 3] += p * vv.w;
      }
    }
    m_run = m_new;
  }
  float inv = 1.0f / l_run;
#pragma unroll
  for (int i = 0; i < 4; i++) {
    float4 o = make_float4(acc[i * 4 + 0] * inv, acc[i * 4 + 1] * inv,
                           acc[i * 4 + 2] * inv, acc[i * 4 + 3] * inv);
    *reinterpret_cast<float4*>(
        &ctx[(bS + q0 + r) * DM + h * DH + c0 + i * 4]) = o;
  }
}

extern "C" void kernel_launch(void* const* d_in, const int* in_sizes, int n_in,
                              void* d_out, int out_size, void* d_ws,
                              size_t ws_size, hipStream_t stream) {
  const float* Xq = (const float*)d_in[0];
  const float* Xk = (const float*)d_in[1];
  const float* Xv = (const float*)d_in[2];
  const int* mask = (const int*)d_in[3];  // jax bool -> harness int32
  const float* edge = (const float*)d_in[4];
  const float* Wq = (const float*)d_in[5];
  const float* Wk = (const float*)d_in[6];
  const float* Wv = (const float*)d_in[7];
  const float* Wfc = (const float*)d_in[8];

  float* out0 = (float*)d_out;                       // [B,S,DM]
  float* out1 = out0 + (size_t)B_ * S_ * DM;         // [B,S,S]

  float* Qp = (float*)d_ws;                          // [B,S,DM] each, 16 MB
  float* Kp = Qp + (size_t)B_ * S_ * DM;
  float* Vp = Kp + (size_t)B_ * S_ * DM;
  float* ctx = Vp + (size_t)B_ * S_ * DM;

  dim3 blk(256);
  dim3 gproj(DM / 64, (B_ * S_) / 64);  // (8, 128)

  gemm_f32<<<gproj, blk, 0, stream>>>(Xq, Wq, Qp, B_ * S_, DM, DM);
  gemm_f32<<<gproj, blk, 0, stream>>>(Xk, Wk, Kp, B_ * S_, DM, DM);
  gemm_f32<<<gproj, blk, 0, stream>>>(Xv, Wv, Vp, B_ * S_, DM, DM);
  flash_attn<<<dim3(S_ / 64, B_ * H_), blk, 0, stream>>>(Qp, Kp, Vp, mask,
                                                         edge, ctx);
  gemm_f32<<<gproj, blk, 0, stream>>>(ctx, Wfc, out0, B_ * S_, DM, DM);
  scores_avg_gemm<<<dim3(S_ / 64, S_ / 64, B_), blk, 0, stream>>>(
      Qp, Kp, mask, edge, out1);
}

// Round 3
// 424.693 us; speedup vs baseline: 3.9963x; 3.9963x over previous
//
#include <hip/hip_runtime.h>
#include <math.h>

#define B_ 8
#define S_ 1024
#define DM 512
#define H_ 8
#define DH 64

typedef _Float16 h4 __attribute__((ext_vector_type(4)));
typedef _Float16 h8 __attribute__((ext_vector_type(8)));
typedef float f4 __attribute__((ext_vector_type(4)));

#define MFMA16(a, b, c) __builtin_amdgcn_mfma_f32_16x16x32_f16(a, b, c, 0, 0, 0)

// ---------------------------------------------------------------------------
// Cast X (f32 row-major) -> f16 row-major. grid (4096, 3), 4 elems/thread.
// ---------------------------------------------------------------------------
__global__ __launch_bounds__(256) void cast_x(
    const float* __restrict__ x0, const float* __restrict__ x1,
    const float* __restrict__ x2, _Float16* __restrict__ y0,
    _Float16* __restrict__ y1, _Float16* __restrict__ y2) {
  const float* x = (blockIdx.y == 0) ? x0 : (blockIdx.y == 1) ? x1 : x2;
  _Float16* y = (blockIdx.y == 0) ? y0 : (blockIdx.y == 1) ? y1 : y2;
  size_t i = (size_t)blockIdx.x * 1024 + (size_t)threadIdx.x * 4;
  float4 v = *(const float4*)(x + i);
  h4 hv = {(_Float16)v.x, (_Float16)v.y, (_Float16)v.z, (_Float16)v.w};
  *(h4*)(y + i) = hv;
}

// ---------------------------------------------------------------------------
// Cast + transpose W [512][512] f32 -> Wt [n][k] f16. grid (8, 8, 4).
// ---------------------------------------------------------------------------
__global__ __launch_bounds__(256) void cast_w(
    const float* __restrict__ w0, const float* __restrict__ w1,
    const float* __restrict__ w2, const float* __restrict__ w3,
    _Float16* __restrict__ t0, _Float16* __restrict__ t1,
    _Float16* __restrict__ t2, _Float16* __restrict__ t3) {
  const float* W;
  _Float16* T;
  switch (blockIdx.z) {
    case 0: W = w0; T = t0; break;
    case 1: W = w1; T = t1; break;
    case 2: W = w2; T = t2; break;
    default: W = w3; T = t3; break;
  }
  __shared__ _Float16 ts[64][72];
  const int t = threadIdx.x;
  const int r = t >> 2, c0 = (t & 3) * 16;
  const int n0 = blockIdx.x * 64, k0 = blockIdx.y * 64;
#pragma unroll
  for (int i = 0; i < 4; i++) {
    float4 v = *(const float4*)&W[(size_t)(k0 + r) * 512 + n0 + c0 + i * 4];
    h4 hv = {(_Float16)v.x, (_Float16)v.y, (_Float16)v.z, (_Float16)v.w};
    *(h4*)&ts[r][c0 + i * 4] = hv;
  }
  __syncthreads();
  alignas(16) _Float16 outv[16];
#pragma unroll
  for (int i = 0; i < 16; i++) outv[i] = ts[c0 + i][r];
  *(uint4*)&T[(size_t)(n0 + r) * 512 + k0 + c0] = *(uint4*)&outv[0];
  *(uint4*)&T[(size_t)(n0 + r) * 512 + k0 + c0 + 8] = *(uint4*)&outv[8];
}

// ---------------------------------------------------------------------------
// Transpose V per (b,h): Vh [b*1024+s][512] head-slice -> Vth [bh*64+d][1024].
// grid (16 s-tiles, 64 bh).
// ---------------------------------------------------------------------------
__global__ __launch_bounds__(256) void transpose_v(
    const _Float16* __restrict__ Vh, _Float16* __restrict__ Vth) {
  const int bh = blockIdx.y, b = bh >> 3, h = bh & 7;
  const int s0 = blockIdx.x * 64;
  __shared__ _Float16 ts[64][72];
  const int t = threadIdx.x;
  const int r = t >> 2, c0 = (t & 3) * 16;
  const size_t src = ((size_t)b * S_ + s0 + r) * DM + h * DH + c0;
  *(uint4*)&ts[r][c0] = *(const uint4*)&Vh[src];
  *(uint4*)&ts[r][c0 + 8] = *(const uint4*)&Vh[src + 8];
  __syncthreads();
  alignas(16) _Float16 outv[16];
#pragma unroll
  for (int i = 0; i < 16; i++) outv[i] = ts[c0 + i][r];  // [d=r][s=c0+i]
  const size_t dst = ((size_t)bh * 64 + r) * S_ + s0 + c0;
  *(uint4*)&Vth[dst] = *(uint4*)&outv[0];
  *(uint4*)&Vth[dst + 8] = *(uint4*)&outv[8];
}

// ---------------------------------------------------------------------------
// f16 MFMA GEMM: C[M][N] = A[M][K] * Bt[N][K]^T. 64x64 tile, 4 waves,
// wave w owns m-strip w*16, all 64 n. 16x16x32 MFMA, k-chunks of 64.
// ---------------------------------------------------------------------------
template <bool F32OUT>
__global__ __launch_bounds__(256) void gemm_h(
    const _Float16* __restrict__ A, const _Float16* __restrict__ Bt,
    void* __restrict__ Cout, int M, int N, int K) {
  __shared__ _Float16 As[64][72], Bs[64][72];
  const int t = threadIdx.x, lane = t & 63, w = t >> 6;
  const int quad = lane >> 4, l16 = lane & 15;
  const int row0 = blockIdx.y * 64, col0 = blockIdx.x * 64;
  f4 acc[4] = {};
  for (int k0 = 0; k0 < K; k0 += 64) {
#pragma unroll
    for (int i = 0; i < 2; i++) {
      int c = t + i * 256;
      int r = c >> 3, cs = (c & 7) * 8;
      *(uint4*)&As[r][cs] = *(const uint4*)&A[(size_t)(row0 + r) * K + k0 + cs];
      *(uint4*)&Bs[r][cs] = *(const uint4*)&Bt[(size_t)(col0 + r) * K + k0 + cs];
    }
    __syncthreads();
    h8 a0 = *(h8*)&As[w * 16 + l16][quad * 8];
    h8 a1 = *(h8*)&As[w * 16 + l16][32 + quad * 8];
#pragma unroll
    for (int n = 0; n < 4; n++) {
      h8 b0 = *(h8*)&Bs[n * 16 + l16][quad * 8];
      h8 b1 = *(h8*)&Bs[n * 16 + l16][32 + quad * 8];
      acc[n] = MFMA16(a0, b0, acc[n]);
      acc[n] = MFMA16(a1, b1, acc[n]);
    }
    __syncthreads();
  }
#pragma unroll
  for (int n = 0; n < 4; n++)
#pragma unroll
    for (int reg = 0; reg < 4; reg++) {
      size_t row = row0 + w * 16 + quad * 4 + reg;
      size_t col = col0 + n * 16 + l16;
      if (F32OUT)
        ((float*)Cout)[row * N + col] = acc[n][reg];
      else
        ((_Float16*)Cout)[row * N + col] = (_Float16)acc[n][reg];
    }
}

// ---------------------------------------------------------------------------
// scores_avg: out1[b,i,j] = mask ? -1e9 : edge + dot512(Q[b,i],K[b,j])/64.
// Same MFMA core, K=512. grid (16 j, 16 i, 8 b).
// ---------------------------------------------------------------------------
__global__ __launch_bounds__(256) void scores_mfma(
    const _Float16* __restrict__ Qh, const _Float16* __restrict__ Kh,
    const int* __restrict__ mask, const float* __restrict__ edge,
    float* __restrict__ out1) {
  const int b = blockIdx.z;
  const int i0 = blockIdx.y * 64, j0 = blockIdx.x * 64;
  const _Float16* A = Qh + (size_t)b * S_ * DM;
  const _Float16* Bt = Kh + (size_t)b * S_ * DM;
  __shared__ _Float16 As[64][72], Bs[64][72];
  const int t = threadIdx.x, lane = t & 63, w = t >> 6;
  const int quad = lane >> 4, l16 = lane & 15;
  f4 acc[4] = {};
  for (int k0 = 0; k0 < DM; k0 += 64) {
#pragma unroll
    for (int i = 0; i < 2; i++) {
      int c = t + i * 256;
      int r = c >> 3, cs = (c & 7) * 8;
      *(uint4*)&As[r][cs] = *(const uint4*)&A[(size_t)(i0 + r) * DM + k0 + cs];
      *(uint4*)&Bs[r][cs] = *(const uint4*)&Bt[(size_t)(j0 + r) * DM + k0 + cs];
    }
    __syncthreads();
    h8 a0 = *(h8*)&As[w * 16 + l16][quad * 8];
    h8 a1 = *(h8*)&As[w * 16 + l16][32 + quad * 8];
#pragma unroll
    for (int n = 0; n < 4; n++) {
      h8 b0 = *(h8*)&Bs[n * 16 + l16][quad * 8];
      h8 b1 = *(h8*)&Bs[n * 16 + l16][32 + quad * 8];
      acc[n] = MFMA16(a0, b0, acc[n]);
      acc[n] = MFMA16(a1, b1, acc[n]);
    }
    __syncthreads();
  }
#pragma unroll
  for (int n = 0; n < 4; n++)
#pragma unroll
    for (int reg = 0; reg < 4; reg++) {
      size_t gi = i0 + w * 16 + quad * 4 + reg;
      size_t gj = j0 + n * 16 + l16;
      size_t idx = ((size_t)b * S_ + gi) * S_ + gj;
      float v = acc[n][reg] * (1.0f / 64.0f) + edge[idx];
      out1[idx] = mask[idx] ? -1e9f : v;
    }
}

// ---------------------------------------------------------------------------
// MFMA flash attention. Block = 64-row Q tile of one (b,h); j-tiles of 64.
// Wave w owns q-rows w*16..w*16+15. P roundtrips LDS (wave-private rows,
// no extra barrier). Online softmax per row via 16-lane shfl reductions.
// ---------------------------------------------------------------------------
__global__ __launch_bounds__(256, 2) void flash_mfma(
    const _Float16* __restrict__ Qh, const _Float16* __restrict__ Kh,
    const _Float16* __restrict__ Vth, const int* __restrict__ mask,
    const float* __restrict__ edge, _Float16* __restrict__ ctxh) {
  __shared__ _Float16 Qs[64][72], Ks[64][72], Vt[64][72], Ps[64][72];
  const int t = threadIdx.x, lane = t & 63, w = t >> 6;
  const int quad = lane >> 4, l16 = lane & 15;
  const int bh = blockIdx.y, b = bh >> 3, h = bh & 7;
  const int q0 = blockIdx.x * 64;
  const size_t bS = (size_t)b * S_;
  const int rqb = w * 16 + quad * 4;  // first of this lane's 4 q-rows (in tile)

#pragma unroll
  for (int i = 0; i < 2; i++) {
    int c = t + i * 256;
    int r = c >> 3, cs = (c & 7) * 8;
    *(uint4*)&Qs[r][cs] = *(const uint4*)&Qh[(bS + q0 + r) * DM + h * DH + cs];
  }
  __syncthreads();
  h8 aq0 = *(h8*)&Qs[w * 16 + l16][quad * 8];
  h8 aq1 = *(h8*)&Qs[w * 16 + l16][32 + quad * 8];

  f4 acco[4] = {};  // O accum: n-tiles over d, C-layout
  float m_run[4], l_run[4];
#pragma unroll
  for (int r = 0; r < 4; r++) {
    m_run[r] = -INFINITY;
    l_run[r] = 0.f;
  }

  for (int kb = 0; kb < S_; kb += 64) {
    __syncthreads();  // previous iter's readers of Ks/Vt done
#pragma unroll
    for (int i = 0; i < 2; i++) {
      int c = t + i * 256;
      int r = c >> 3, cs = (c & 7) * 8;
      *(uint4*)&Ks[r][cs] =
          *(const uint4*)&Kh[(bS + kb + r) * DM + h * DH + cs];
      *(uint4*)&Vt[r][cs] =
          *(const uint4*)&Vth[((size_t)bh * 64 + r) * S_ + kb + cs];
    }
    __syncthreads();
    // ---- QK^T ----
    f4 accs[4] = {};
#pragma unroll
    for (int n = 0; n < 4; n++) {
      h8 b0 = *(h8*)&Ks[n * 16 + l16][quad * 8];
      h8 b1 = *(h8*)&Ks[n * 16 + l16][32 + quad * 8];
      accs[n] = MFMA16(aq0, b0, accs[n]);
      accs[n] = MFMA16(aq1, b1, accs[n]);
    }
    // ---- mask + edge ----
    float sv[4][4];
#pragma unroll
    for (int n = 0; n < 4; n++)
#pragma unroll
      for (int reg = 0; reg < 4; reg++) {
        size_t eidx = (bS + q0 + rqb + reg) * (size_t)S_ + kb + n * 16 + l16;
        float s = accs[n][reg] * 0.125f + edge[eidx];
        sv[n][reg] = mask[eidx] ? -1e9f : s;
      }
    // ---- online softmax (per q-row = per reg, reduce over n and 16 lanes) --
#pragma unroll
    for (int reg = 0; reg < 4; reg++) {
      float mx = fmaxf(fmaxf(sv[0][reg], sv[1][reg]),
                       fmaxf(sv[2][reg], sv[3][reg]));
#pragma unroll
      for (int off = 1; off < 16; off <<= 1)
        mx = fmaxf(mx, __shfl_xor(mx, off, 16));
      float mnew = fmaxf(m_run[reg], mx);
      float alpha = __expf(m_run[reg] - mnew);  // exp(-inf)=0 first tile
      m_run[reg] = mnew;
      float psum = 0.f;
#pragma unroll
      for (int n = 0; n < 4; n++) {
        float p = __expf(sv[n][reg] - mnew);
        sv[n][reg] = p;
        psum += p;
      }
#pragma unroll
      for (int off = 1; off < 16; off <<= 1) psum += __shfl_xor(psum, off, 16);
      l_run[reg] = l_run[reg] * alpha + psum;
#pragma unroll
      for (int n = 0; n < 4; n++) acco[n][reg] *= alpha;
    }
    // ---- P -> LDS (wave-private rows; same-wave write->read needs no barrier)
#pragma unroll
    for (int n = 0; n < 4; n++)
#pragma unroll
      for (int reg = 0; reg < 4; reg++)
        Ps[rqb + reg][n * 16 + l16] = (_Float16)sv[n][reg];
    // ---- P @ V ----
    h8 ap0 = *(h8*)&Ps[w * 16 + l16][quad * 8];
    h8 ap1 = *(h8*)&Ps[w * 16 + l16][32 + quad * 8];
#pragma unroll
    for (int n = 0; n < 4; n++) {
      h8 bv0 = *(h8*)&Vt[n * 16 + l16][quad * 8];
      h8 bv1 = *(h8*)&Vt[n * 16 + l16][32 + quad * 8];
      acco[n] = MFMA16(ap0, bv0, acco[n]);
      acco[n] = MFMA16(ap1, bv1, acco[n]);
    }
  }
  // ---- finalize ----
#pragma unroll
  for (int n = 0; n < 4; n++)
#pragma unroll
    for (int reg = 0; reg < 4; reg++) {
      float o = acco[n][reg] / l_run[reg];
      ctxh[(bS + q0 + rqb + reg) * DM + h * DH + n * 16 + l16] = (_Float16)o;
    }
}

extern "C" void kernel_launch(void* const* d_in, const int* in_sizes, int n_in,
                              void* d_out, int out_size, void* d_ws,
                              size_t ws_size, hipStream_t stream) {
  const float* Xq = (const float*)d_in[0];
  const float* Xk = (const float*)d_in[1];
  const float* Xv = (const float*)d_in[2];
  const int* mask = (const int*)d_in[3];
  const float* edge = (const float*)d_in[4];
  const float* Wq = (const float*)d_in[5];
  const float* Wk = (const float*)d_in[6];
  const float* Wv = (const float*)d_in[7];
  const float* Wfc = (const float*)d_in[8];

  float* out0 = (float*)d_out;                // [B,S,DM] f32
  float* out1 = out0 + (size_t)B_ * S_ * DM;  // [B,S,S] f32

  const size_t NE = (size_t)B_ * S_ * DM;  // 4.19M elements
  char* ws = (char*)d_ws;
  _Float16* Qh = (_Float16*)ws;                    // 8.4 MB
  _Float16* Kh = Qh + NE;                          // 8.4 MB
  _Float16* Vh = Kh + NE;                          // 8.4 MB
  _Float16* Xhq = Vh + NE;                         // 8.4 MB (later: ctxh)
  _Float16* Xhk = Xhq + NE;                        // 8.4 MB (later: Vth)
  _Float16* Xhv = Xhk + NE;                        // 8.4 MB
  _Float16* Wt = Xhv + NE;                         // 4 x 0.5 MB
  _Float16* Wtq = Wt, *Wtk = Wt + 512 * 512, *Wtv = Wt + 2 * 512 * 512,
            *Wtf = Wt + 3 * 512 * 512;
  _Float16* ctxh = Xhq;  // alias: Xhq dead after Q-projection
  _Float16* Vth = Xhk;   // alias: Xhk dead after K-projection

  dim3 blk(256);
  cast_x<<<dim3(4096, 3), blk, 0, stream>>>(Xq, Xk, Xv, Xhq, Xhk, Xhv);
  cast_w<<<dim3(8, 8, 4), blk, 0, stream>>>(Wq, Wk, Wv, Wfc, Wtq, Wtk, Wtv,
                                            Wtf);
  dim3 gp(DM / 64, (B_ * S_) / 64);  // (8, 128)
  gemm_h<false><<<gp, blk, 0, stream>>>(Xhq, Wtq, Qh, B_ * S_, DM, DM);
  gemm_h<false><<<gp, blk, 0, stream>>>(Xhk, Wtk, Kh, B_ * S_, DM, DM);
  gemm_h<false><<<gp, blk, 0, stream>>>(Xhv, Wtv, Vh, B_ * S_, DM, DM);
  transpose_v<<<dim3(16, 64), blk, 0, stream>>>(Vh, Vth);
  flash_mfma<<<dim3(16, 64), blk, 0, stream>>>(Qh, Kh, Vth, mask, edge, ctxh);
  gemm_h<true><<<gp, blk, 0, stream>>>(ctxh, Wtf, out0, B_ * S_, DM, DM);
  scores_mfma<<<dim3(16, 16, 8), blk, 0, stream>>>(Qh, Kh, mask, edge, out1);
}